// Round 7
// baseline (186.419 us; speedup 1.0000x reference)
//
#include <hip/hip_runtime.h>
#include <stdint.h>

typedef unsigned short u16;
typedef __bf16 bf16x8 __attribute__((ext_vector_type(8)));
typedef __bf16 bf16x4v __attribute__((ext_vector_type(4)));
typedef float f32x4 __attribute__((ext_vector_type(4)));

typedef __attribute__((address_space(3))) uint32_t lds_u32;
typedef __attribute__((address_space(1))) uint32_t glb_u32;

__device__ __forceinline__ f32x4 mfma16(bf16x8 a, bf16x8 b, f32x4 c) {
    return __builtin_amdgcn_mfma_f32_16x16x32_bf16(a, b, c, 0, 0, 0);
}

// 4x f32 -> bf16 via native cvt (RNE), reinterpreted as ushort4
__device__ __forceinline__ ushort4 pk4(float a, float b, float c, float d) {
    bf16x4v v;
    v[0] = (__bf16)a; v[1] = (__bf16)b; v[2] = (__bf16)c; v[3] = (__bf16)d;
    union { bf16x4v v; ushort4 u; } cv; cv.v = v; return cv.u;
}

// raw v_exp_f32 (skip ocml wrapper)
__device__ __forceinline__ float fexp2(float x) {
    return __builtin_amdgcn_exp2f(x);
}

// async global->LDS, 16B per lane (LDS dest = wave base + lane*16)
__device__ __forceinline__ void async16(const u16* g, u16* l) {
    __builtin_amdgcn_global_load_lds((glb_u32*)(uintptr_t)(const void*)g,
                                     (lds_u32*)l, 16, 0, 0);
}

// ---------------------------------------------------------------------------
// fp32 -> bf16 casts (unchanged)
// ---------------------------------------------------------------------------
__global__ __launch_bounds__(256) void cast_all(
    const float* __restrict__ x,
    const float* __restrict__ w0, const float* __restrict__ w1,
    const float* __restrict__ w2, const float* __restrict__ w3,
    u16* __restrict__ xo, u16* __restrict__ o0, u16* __restrict__ o1,
    u16* __restrict__ o2, u16* __restrict__ o3)
{
    const int s = blockIdx.y;
    const int i = (blockIdx.x * 256 + threadIdx.x) * 4;
    if (s == 0) {
#pragma unroll
        for (int c = 0; c < 4; ++c) {
            const int j = i + c * (1 << 20);
            float4 v = *(const float4*)(x + j);
            *(ushort4*)(xo + j) = pk4(v.x, v.y, v.z, v.w);
        }
    } else {
        const float* in = s == 1 ? w0 : (s == 2 ? w1 : (s == 3 ? w2 : w3));
        u16* out       = s == 1 ? o0 : (s == 2 ? o1 : (s == 3 ? o2 : o3));
        float4 v = *(const float4*)(in + i);
        *(ushort4*)(out + i) = pk4(v.x, v.y, v.z, v.w);
    }
}

// ---------------------------------------------------------------------------
// QKV GEMM, round 20: BK 64 -> 32 with double-buffer.
// Round-16 dbuf (64 KiB LDS) dropped co-residency to 2 blocks/CU: the
// 768-block grid ran in ~1.5 scheduling rounds (512 + 256 backfill), eating
// the pipeline gain (48.3 -> only 43.5). BK=32 dbuf = 32 KiB LDS -> 3
// blocks/CU -> all 768 blocks co-resident (exact 3x256, zero tail) AND
// 12 waves/CU of TLP. 32 K-steps, 16 MFMA each; prefetch order kept.
// Swizzle (4 chunks/row): LDS[R][dc] = G[R][dc ^ ((R>>1)&3)]; read
// sl = quad ^ ((r>>1)&3) -> 64-lane b128 read touches each bank exactly 8x
// (conflict-free). Staging source permutation is lane-only:
// scc = (l&3) ^ ((l>>3)&3). Epilogues (incl. VT transpose alias) unchanged.
// ---------------------------------------------------------------------------
__global__ __launch_bounds__(256) void gemm_qkv(
    const u16* __restrict__ A,
    const u16* __restrict__ W0, const u16* __restrict__ W1, const u16* __restrict__ W2,
    const float* __restrict__ B0, const float* __restrict__ B1, const float* __restrict__ B2,
    u16* __restrict__ O0, u16* __restrict__ O1,
    u16* __restrict__ VT,
    int M, int N, int K)
{
    const int x = blockIdx.x & 7;
    const int L = blockIdx.x >> 3;                 // 0..95
    const int tm = (8 * (x >> 1) + (L & 7)) << 7;  // 32 tm tiles
    const int tnsel = 12 * (x & 1) + (L >> 3);     // 0..23
    const int sel = tnsel >> 3;
    const int tn  = (tnsel & 7) << 7;

    const u16* W      = sel == 0 ? W0 : (sel == 1 ? W1 : W2);
    const float* bias = sel == 0 ? B0 : (sel == 1 ? B1 : B2);
    u16* O            = sel == 0 ? O0 : O1;        // sel==2 -> VT path

    __shared__ __attribute__((aligned(16))) u16 As[2][128 * 32];
    __shared__ __attribute__((aligned(16))) u16 Bs[2][128 * 32];
    u16 (*Tb)[136] = (u16 (*)[136])As;             // union: post-K-loop only

    const int tid  = threadIdx.x;
    const int lane = tid & 63;
    const int w    = tid >> 6;
    const int l15  = lane & 15;
    const int quad = lane >> 4;

    const int wm = (w >> 1) << 6;
    const int wn = (w & 1) << 6;

    f32x4 acc[4][4];
#pragma unroll
    for (int i = 0; i < 4; ++i)
#pragma unroll
        for (int j = 0; j < 4; ++j) acc[i][j] = f32x4{0.f, 0.f, 0.f, 0.f};

    // staging decomposition: per async16 call, wave covers 16 rows (1 KiB).
    // lane l -> row offset l>>2, dest chunk l&3, source chunk lane-only perm.
    const int srow = lane >> 2;                    // 0..15
    const int sch  = ((lane & 3) ^ ((lane >> 3) & 3)) << 3;
    const u16* Ag = A + (size_t)(tm + srow) * K + sch;
    const u16* Wg = W + (size_t)(tn + srow) * K + sch;
    u16* Al = &As[0][0] + lane * 8;
    u16* Bl = &Bs[0][0] + lane * 8;

#define QKV_STAGE(bi, k0)                                                      \
    do {                                                                       \
        _Pragma("unroll")                                                      \
        for (int c = 0; c < 2; ++c) {                                          \
            const int blk = c * 4 + w;                                         \
            async16(Ag + (k0) + (size_t)blk * 16 * K,                          \
                    Al + (bi) * 4096 + blk * 512);                             \
            async16(Wg + (k0) + (size_t)blk * 16 * K,                          \
                    Bl + (bi) * 4096 + blk * 512);                             \
        }                                                                      \
    } while (0)

    const int nt = K >> 5;                         // 32
    QKV_STAGE(0, 0);
    for (int t = 0; t < nt; ++t) {
        const int cur = t & 1;
        asm volatile("s_waitcnt vmcnt(0)" ::: "memory");
        __syncthreads();
        if (t + 1 < nt) QKV_STAGE(cur ^ 1, (t + 1) * 32);
        const u16* Ab = As[cur];
        const u16* Bb = Bs[cur];
        bf16x8 a[4], b[4];
#pragma unroll
        for (int i = 0; i < 4; ++i) {
            const int r  = wm + 16 * i + l15;
            const int sl = quad ^ ((r >> 1) & 3);
            a[i] = *(const bf16x8*)&Ab[r * 32 + sl * 8];
        }
#pragma unroll
        for (int j = 0; j < 4; ++j) {
            const int r  = wn + 16 * j + l15;
            const int sl = quad ^ ((r >> 1) & 3);
            b[j] = *(const bf16x8*)&Bb[r * 32 + sl * 8];
        }
#pragma unroll
        for (int i = 0; i < 4; ++i)
#pragma unroll
            for (int j = 0; j < 4; ++j)
                acc[i][j] = mfma16(a[i], b[j], acc[i][j]);
    }
#undef QKV_STAGE

    if (sel == 2) {
        const int bb = tm >> 11;
        const int s0 = tm & 2047;
        const size_t vtb = ((size_t)bb << 10) + tn;
        for (int c32 = 0; c32 < 128; c32 += 32) {
            __syncthreads();
            if ((c32 >> 6) == (wn >> 6)) {
                const int j0 = (c32 >> 4) & 2;
#pragma unroll
                for (int jj = 0; jj < 2; ++jj) {
                    const int j  = j0 + jj;
                    const int cc = jj * 16 + l15;
                    const float bj = bias[tn + wn + 16 * j + l15];
#pragma unroll
                    for (int i = 0; i < 4; ++i) {
                        const int rr = wm + 16 * i + quad * 4;
                        *(ushort4*)&Tb[cc][rr] =
                            pk4(acc[i][j][0] + bj, acc[i][j][1] + bj,
                                acc[i][j][2] + bj, acc[i][j][3] + bj);
                    }
                }
            }
            __syncthreads();
            {
                const int c  = tid >> 3;
                const int ss = (tid & 7) * 16;
                uint4 v0 = *(const uint4*)&Tb[c][ss];
                uint4 v1 = *(const uint4*)&Tb[c][ss + 8];
                u16* dst = &VT[(vtb + c32 + c) * 2048 + s0 + ss];
                *(uint4*)dst       = v0;
                *(uint4*)(dst + 8) = v1;
            }
        }
    } else {
#pragma unroll
        for (int j = 0; j < 4; ++j) {
            const int col = tn + wn + 16 * j + l15;
            const float bj = bias[col];
#pragma unroll
            for (int i = 0; i < 4; ++i) {
                const int row = tm + wm + 16 * i + quad * 4;
#pragma unroll
                for (int r = 0; r < 4; ++r) {
                    union { float f; unsigned u; } v; v.f = acc[i][j][r] + bj;
                    unsigned rn = v.u + 0x7FFFu + ((v.u >> 16) & 1u);
                    O[(size_t)(row + r) * N + col] = (u16)(rn >> 16);
                }
            }
        }
    }
}

// ---------------------------------------------------------------------------
// Output projection GEMM (frozen from round 16; 48 KiB -> 3/CU, 512 blocks
// already fully co-resident -> no tail)
// ---------------------------------------------------------------------------
__global__ __launch_bounds__(256) void gemm_out64(
    const u16* __restrict__ A, const u16* __restrict__ W,
    const float* __restrict__ bias, float* __restrict__ O,
    int M, int N, int K)
{
    __shared__ __attribute__((aligned(16))) u16 As[2][128 * 64];
    __shared__ __attribute__((aligned(16))) u16 Bs[2][64 * 64];

    const int x = blockIdx.x & 7;
    const int L = blockIdx.x >> 3;                 // 0..63
    const int tm = (8 * (x >> 1) + (L & 7)) << 7;  // 32 tiles
    const int tn = (8 * (x & 1) + (L >> 3)) << 6;  // 16 tiles

    const int tid  = threadIdx.x;
    const int lane = tid & 63;
    const int w    = tid >> 6;
    const int l15  = lane & 15;
    const int quad = lane >> 4;

    const int wm = (w >> 1) << 6;
    const int wn = (w & 1) << 5;

    f32x4 acc[4][2];
#pragma unroll
    for (int i = 0; i < 4; ++i)
#pragma unroll
        for (int j = 0; j < 2; ++j) acc[i][j] = f32x4{0.f, 0.f, 0.f, 0.f};

    const int lr  = lane >> 3;
    const int lcc = lane & 7;
    const int scc = lcc ^ lr;
    const u16* Ag = A + (size_t)(tm + 32 * w + lr) * K + scc * 8;
    const u16* Wg = W + (size_t)(tn + 16 * w + lr) * K + scc * 8;
    u16* Al = &As[0][(32 * w + lr) * 64 + lcc * 8];
    u16* Bl = &Bs[0][(16 * w + lr) * 64 + lcc * 8];

#define OUT_STAGE(bi, k0)                                                      \
    do {                                                                       \
        _Pragma("unroll")                                                      \
        for (int m = 0; m < 4; ++m)                                            \
            async16(Ag + (k0) + (size_t)m * 8 * K, Al + (bi) * 8192 + m * 512);\
        _Pragma("unroll")                                                      \
        for (int m = 0; m < 2; ++m)                                            \
            async16(Wg + (k0) + (size_t)m * 8 * K, Bl + (bi) * 4096 + m * 512);\
    } while (0)

    const int nt = K >> 6;                         // 16
    OUT_STAGE(0, 0);
    for (int t = 0; t < nt; ++t) {
        const int cur = t & 1;
        asm volatile("s_waitcnt vmcnt(0)" ::: "memory");
        __syncthreads();
        if (t + 1 < nt) OUT_STAGE(cur ^ 1, (t + 1) * 64);
        const u16* Ab = As[cur];
        const u16* Bb = Bs[cur];
#pragma unroll
        for (int kk = 0; kk < 2; ++kk) {
            bf16x8 a[4], b[2];
#pragma unroll
            for (int i = 0; i < 4; ++i) {
                const int r  = wm + 16 * i + l15;
                const int sl = (kk * 4 + quad) ^ (r & 7);
                a[i] = *(const bf16x8*)&Ab[r * 64 + sl * 8];
            }
#pragma unroll
            for (int j = 0; j < 2; ++j) {
                const int r  = wn + 16 * j + l15;
                const int sl = (kk * 4 + quad) ^ (r & 7);
                b[j] = *(const bf16x8*)&Bb[r * 64 + sl * 8];
            }
#pragma unroll
            for (int i = 0; i < 4; ++i)
#pragma unroll
                for (int j = 0; j < 2; ++j)
                    acc[i][j] = mfma16(a[i], b[j], acc[i][j]);
        }
    }
#undef OUT_STAGE

#pragma unroll
    for (int j = 0; j < 2; ++j) {
        const int col = tn + wn + 16 * j + l15;
        const float bj = bias[col];
#pragma unroll
        for (int i = 0; i < 4; ++i) {
            const int row = tm + wm + 16 * i + quad * 4;
#pragma unroll
            for (int r = 0; r < 4; ++r)
                O[(size_t)(row + r) * N + col] = acc[i][j][r] + bj;
        }
    }
}

// ---------------------------------------------------------------------------
// attn11 (frozen from round 19)
// ---------------------------------------------------------------------------
__device__ __forceinline__ bf16x8 rdt(const u16* base, int t, int l15, int cc) {
    const int r = t * 16 + l15;
    const int c = (cc & 3) ^ ((r >> 1) & 3);
    return *(const bf16x8*)(base + (cc >> 2) * 2048 + r * 32 + c * 8);
}

#define QK_EXP(Z, PROW, QG, MASKED, RSV, KB)                                   \
    do {                                                                       \
        _Pragma("unroll")                                                      \
        for (int t = 0; t < 4; ++t) {                                          \
            float e0 = fexp2(fmaf((Z)[t][0], SC, -16.0f));                     \
            float e1 = fexp2(fmaf((Z)[t][1], SC, -16.0f));                     \
            float e2 = fexp2(fmaf((Z)[t][2], SC, -16.0f));                     \
            float e3 = fexp2(fmaf((Z)[t][3], SC, -16.0f));                     \
            if (MASKED) {                                                      \
                const int kb = (KB) + t * 16 + quad * 4;                       \
                if (kb + 0 > (QG)) e0 = 0.f;                                   \
                if (kb + 1 > (QG)) e1 = 0.f;                                   \
                if (kb + 2 > (QG)) e2 = 0.f;                                   \
                if (kb + 3 > (QG)) e3 = 0.f;                                   \
            }                                                                  \
            (RSV)[0] += e0; (RSV)[1] += e1;                                    \
            (RSV)[2] += e2; (RSV)[3] += e3;                                    \
            *(ushort4*)((PROW) + (((2 * t + whi) ^ sl7) << 3) + woff) =        \
                pk4(e0, e1, e2, e3);                                           \
        }                                                                      \
    } while (0)

__global__ __launch_bounds__(256, 4) void attn11(
    const u16* __restrict__ Q, const u16* __restrict__ Kb,
    const u16* __restrict__ VT, u16* __restrict__ ctx)
{
    __shared__ __attribute__((aligned(16))) u16 Kt[2][4096];
    __shared__ __attribute__((aligned(16))) u16 Vt[2][4096];
    __shared__ __attribute__((aligned(16))) u16 Pt[4][16][64];

    const int tid  = threadIdx.x;
    const int lane = tid & 63;
    const int wid  = tid >> 6;
    const int l15  = lane & 15;
    const int quad = lane >> 4;
    const int sl7  = l15 & 7;
    const int whi  = quad >> 1;
    const int woff = (quad & 1) * 4;

    const int hb = blockIdx.x & 31;
    const int h  = hb & 15, b = hb >> 4;
    const int ti = blockIdx.x >> 5;          // 0..31
    const int tq = ti >> 3, to = ti & 7;
    const int g4 = (tq == 0) ? to
                 : (tq == 1) ? (15 - to)
                 : (tq == 2) ? (16 + to)
                 :             (31 - to);    // quartet index 0..31
    const int s  = 4 * g4 + wid;             // Q group 0..127
    const int NT = g4 + 1;                   // KV 64-tiles (same for all waves)

    const size_t rowbase = (size_t)b * 2048;
    const int cbase = h * 64;
    const u16* kbase = Kb + rowbase * 1024 + cbase;
    const u16* vbase = VT + ((size_t)b * 1024 + cbase) * 2048;

    const int qg = s * 16 + l15;
    const u16* qp = Q + (rowbase + qg) * 1024 + cbase + quad * 8;
    const bf16x8 q0 = *(const bf16x8*)qp, q1 = *(const bf16x8*)(qp + 32);

    const int sr  = tid >> 2;
    const int sc0 = (((tid & 3) ^ ((sr >> 1) & 3)) << 3);
    const u16* kg = kbase + (size_t)sr * 1024 + sc0;
    const u16* vg = vbase + (size_t)sr * 2048 + sc0;

    f32x4 o[4];
#pragma unroll
    for (int i = 0; i < 4; ++i) o[i] = f32x4{0, 0, 0, 0};
    f32x4 rsv = {0, 0, 0, 0};
    const float SC = 0.18033688011112042f;

    u16 (*ptw)[64] = Pt[wid];
    u16* const pr = &ptw[l15][0];
    const int pof0 = (quad ^ sl7) << 3;
    const int pof1 = ((quad | 4) ^ sl7) << 3;

#define STAGE(buf, Tt)                                                         \
    do {                                                                       \
        const u16* kq = kg + (size_t)(Tt) * 65536;                             \
        const u16* vq = vg + (Tt) * 64;                                        \
        async16(kq,      &Kt[buf][tid * 8]);                                   \
        async16(kq + 32, &Kt[buf][2048 + tid * 8]);                            \
        async16(vq,      &Vt[buf][tid * 8]);                                   \
        async16(vq + 32, &Vt[buf][2048 + tid * 8]);                            \
    } while (0)

    STAGE(0, 0);

    for (int T = 0; T < NT; ++T) {
        const int cur = T & 1;
        asm volatile("s_waitcnt vmcnt(0)" ::: "memory");
        __syncthreads();
        if (T + 1 < NT) STAGE(cur ^ 1, T + 1);

        const u16* KT = Kt[cur];
        const u16* VL = Vt[cur];

        // ---- QK^T ----
        f32x4 z[4];
        __builtin_amdgcn_s_setprio(1);
#pragma unroll
        for (int t = 0; t < 4; ++t) {
            const bf16x8 kA = rdt(KT, t, l15, quad);
            const bf16x8 kB = rdt(KT, t, l15, quad + 4);
            f32x4 zz = {0, 0, 0, 0};
            zz = mfma16(kA, q0, zz);
            zz = mfma16(kB, q1, zz);
            z[t] = zz;
        }
        __builtin_amdgcn_s_setprio(0);

        // ---- exp + pack (mask only on the diagonal tile) ----
        if (T == NT - 1) QK_EXP(z, pr, qg, 1, rsv, T * 64);
        else             QK_EXP(z, pr, qg, 0, rsv, T * 64);

        // ---- P fragments ----
        const bf16x8 pb0 = *(const bf16x8*)(pr + pof0);
        const bf16x8 pb1 = *(const bf16x8*)(pr + pof1);

        // ---- PV ----
        __builtin_amdgcn_s_setprio(1);
#pragma unroll
        for (int t = 0; t < 4; ++t) {
            const bf16x8 vA = rdt(VL, t, l15, quad);
            const bf16x8 vB = rdt(VL, t, l15, quad + 4);
            o[t] = mfma16(vA, pb0, o[t]);
            o[t] = mfma16(vB, pb1, o[t]);
        }
        __builtin_amdgcn_s_setprio(0);
    }
#undef STAGE

    float rs = (rsv[0] + rsv[1]) + (rsv[2] + rsv[3]);
    rs += __shfl_xor(rs, 16); rs += __shfl_xor(rs, 32);
    const float inv = 1.0f / rs;
#pragma unroll
    for (int t = 0; t < 4; ++t) {
        *(ushort4*)&ctx[(rowbase + qg) * 1024 + cbase + t * 16 + quad * 4] =
            pk4(o[t][0] * inv, o[t][1] * inv, o[t][2] * inv, o[t][3] * inv);
    }
}

extern "C" void kernel_launch(void* const* d_in, const int* in_sizes, int n_in,
                              void* d_out, int out_size, void* d_ws, size_t ws_size,
                              hipStream_t stream) {
    const float* x  = (const float*)d_in[0];
    const float* Wq = (const float*)d_in[1];
    const float* bq = (const float*)d_in[2];
    const float* Wk = (const float*)d_in[3];
    const float* bk = (const float*)d_in[4];
    const float* Wv = (const float*)d_in[5];
    const float* bv = (const float*)d_in[6];
    const float* Wo = (const float*)d_in[7];
    const float* bo = (const float*)d_in[8];
    float* out = (float*)d_out;

    const int N = 1024, K = 1024;
    const int M = in_sizes[0] / K;           // 4096
    const size_t MN = (size_t)M * N;
    const size_t WN = (size_t)N * K;

    u16* xb  = (u16*)d_ws;
    u16* wqb = xb  + MN;
    u16* wkb = wqb + WN;
    u16* wvb = wkb + WN;
    u16* wob = wvb + WN;
    u16* q   = wob + WN;
    u16* kb  = q   + MN;
    u16* vt  = kb  + MN;                     // V^T: [b*1024 + h*64 + d][s]
    u16* ctx = q;                            // alias: disjoint per-wave strips

    cast_all<<<dim3(1024, 5), 256, 0, stream>>>(
        x, Wq, Wk, Wv, Wo, xb, wqb, wkb, wvb, wob);

    gemm_qkv<<<dim3(768), 256, 0, stream>>>(
        xb, wqb, wkb, wvb, bq, bk, bv, q, kb, vt, M, N, K);

    attn11<<<dim3(1024), 256, 0, stream>>>(q, kb, vt, ctx);

    gemm_out64<<<dim3(512), 256, 0, stream>>>(
        ctx, wob, bo, out, M, N, K);
}

// Round 8
// 179.669 us; speedup vs baseline: 1.0376x; 1.0376x over previous
//
#include <hip/hip_runtime.h>
#include <stdint.h>

typedef unsigned short u16;
typedef __bf16 bf16x8 __attribute__((ext_vector_type(8)));
typedef __bf16 bf16x4v __attribute__((ext_vector_type(4)));
typedef float f32x4 __attribute__((ext_vector_type(4)));

typedef __attribute__((address_space(3))) uint32_t lds_u32;
typedef __attribute__((address_space(1))) uint32_t glb_u32;

__device__ __forceinline__ f32x4 mfma16(bf16x8 a, bf16x8 b, f32x4 c) {
    return __builtin_amdgcn_mfma_f32_16x16x32_bf16(a, b, c, 0, 0, 0);
}

// 4x f32 -> bf16 via native cvt (RNE), reinterpreted as ushort4
__device__ __forceinline__ ushort4 pk4(float a, float b, float c, float d) {
    bf16x4v v;
    v[0] = (__bf16)a; v[1] = (__bf16)b; v[2] = (__bf16)c; v[3] = (__bf16)d;
    union { bf16x4v v; ushort4 u; } cv; cv.v = v; return cv.u;
}

// raw v_exp_f32 (skip ocml wrapper)
__device__ __forceinline__ float fexp2(float x) {
    return __builtin_amdgcn_exp2f(x);
}

// async global->LDS, 16B per lane (LDS dest = wave base + lane*16)
__device__ __forceinline__ void async16(const u16* g, u16* l) {
    __builtin_amdgcn_global_load_lds((glb_u32*)(uintptr_t)(const void*)g,
                                     (lds_u32*)l, 16, 0, 0);
}

// ---------------------------------------------------------------------------
// fp32 -> bf16 casts (unchanged)
// ---------------------------------------------------------------------------
__global__ __launch_bounds__(256) void cast_all(
    const float* __restrict__ x,
    const float* __restrict__ w0, const float* __restrict__ w1,
    const float* __restrict__ w2, const float* __restrict__ w3,
    u16* __restrict__ xo, u16* __restrict__ o0, u16* __restrict__ o1,
    u16* __restrict__ o2, u16* __restrict__ o3)
{
    const int s = blockIdx.y;
    const int i = (blockIdx.x * 256 + threadIdx.x) * 4;
    if (s == 0) {
#pragma unroll
        for (int c = 0; c < 4; ++c) {
            const int j = i + c * (1 << 20);
            float4 v = *(const float4*)(x + j);
            *(ushort4*)(xo + j) = pk4(v.x, v.y, v.z, v.w);
        }
    } else {
        const float* in = s == 1 ? w0 : (s == 2 ? w1 : (s == 3 ? w2 : w3));
        u16* out       = s == 1 ? o0 : (s == 2 ? o1 : (s == 3 ? o2 : o3));
        float4 v = *(const float4*)(in + i);
        *(ushort4*)(out + i) = pk4(v.x, v.y, v.z, v.w);
    }
}

// ---------------------------------------------------------------------------
// QKV GEMM, round 21: REVERT to round-16 structure (BK=64, dbuf, prefetch --
// the measured-best ~43.5us; round-20's BK=32 starved the latency window,
// 50.1us) + PERSISTENT 2-tile grid: 512 blocks; block i<256 also processes
// tile 512+i ((512+i)&7 == i&7 -> same XCD octant, L2 locality kept).
// Under the dispatch model (CU co-hosts blocks i and i+256) every CU gets
// {2-tile, 1-tile} = 3 tiles uniformly -> no 768-on-512-slot backfill tail.
// ---------------------------------------------------------------------------
__global__ __launch_bounds__(256) void gemm_qkv(
    const u16* __restrict__ A,
    const u16* __restrict__ W0, const u16* __restrict__ W1, const u16* __restrict__ W2,
    const float* __restrict__ B0, const float* __restrict__ B1, const float* __restrict__ B2,
    u16* __restrict__ O0, u16* __restrict__ O1,
    u16* __restrict__ VT,
    int M, int N, int K)
{
    __shared__ __attribute__((aligned(16))) u16 As[2][128 * 64];
    __shared__ __attribute__((aligned(16))) u16 Bs[2][128 * 64];
    u16 (*Tb)[136] = (u16 (*)[136])As;             // union: post-K-loop only

    const int tid  = threadIdx.x;
    const int lane = tid & 63;
    const int w    = tid >> 6;
    const int l15  = lane & 15;
    const int quad = lane >> 4;

    const int wm = (w >> 1) << 6;
    const int wn = (w & 1) << 6;

    const int lr  = lane >> 3;                     // 0..7
    const int lcc = lane & 7;                      // dest chunk
    const int scc = lcc ^ lr;                      // source chunk (row&7 == lr)

    const int npass = (blockIdx.x < 256) ? 2 : 1;

    for (int pass = 0; pass < npass; ++pass) {
        if (pass) __syncthreads();                 // protect As/Tb reuse

        const int id = pass == 0 ? blockIdx.x : 512 + blockIdx.x;
        const int x = id & 7;
        const int L = id >> 3;                     // 0..95
        const int tm = (8 * (x >> 1) + (L & 7)) << 7;
        const int tnsel = 12 * (x & 1) + (L >> 3); // 0..23
        const int sel = tnsel >> 3;
        const int tn  = (tnsel & 7) << 7;

        const u16* W      = sel == 0 ? W0 : (sel == 1 ? W1 : W2);
        const float* bias = sel == 0 ? B0 : (sel == 1 ? B1 : B2);
        u16* O            = sel == 0 ? O0 : O1;    // sel==2 -> VT path

        f32x4 acc[4][4];
#pragma unroll
        for (int i = 0; i < 4; ++i)
#pragma unroll
            for (int j = 0; j < 4; ++j) acc[i][j] = f32x4{0.f, 0.f, 0.f, 0.f};

        const u16* Ag = A + (size_t)(tm + 32 * w + lr) * K + scc * 8;
        const u16* Wg = W + (size_t)(tn + 32 * w + lr) * K + scc * 8;
        u16* Al = &As[0][(32 * w + lr) * 64 + lcc * 8];
        u16* Bl = &Bs[0][(32 * w + lr) * 64 + lcc * 8];

#define QKV_STAGE(bi, k0)                                                      \
    do {                                                                       \
        _Pragma("unroll")                                                      \
        for (int m = 0; m < 4; ++m) {                                          \
            async16(Ag + (k0) + (size_t)m * 8 * K, Al + (bi) * 8192 + m * 512);\
            async16(Wg + (k0) + (size_t)m * 8 * K, Bl + (bi) * 8192 + m * 512);\
        }                                                                      \
    } while (0)

        const int nt = K >> 6;                     // 16
        QKV_STAGE(0, 0);
        for (int t = 0; t < nt; ++t) {
            const int cur = t & 1;
            asm volatile("s_waitcnt vmcnt(0)" ::: "memory");
            __syncthreads();
            if (t + 1 < nt) QKV_STAGE(cur ^ 1, (t + 1) * 64);
            const u16* Ab = As[cur];
            const u16* Bb = Bs[cur];
#pragma unroll
            for (int kk = 0; kk < 2; ++kk) {
                bf16x8 a[4], b[4];
#pragma unroll
                for (int i = 0; i < 4; ++i) {
                    const int r  = wm + 16 * i + l15;
                    const int sl = (kk * 4 + quad) ^ (r & 7);
                    a[i] = *(const bf16x8*)&Ab[r * 64 + sl * 8];
                }
#pragma unroll
                for (int j = 0; j < 4; ++j) {
                    const int r  = wn + 16 * j + l15;
                    const int sl = (kk * 4 + quad) ^ (r & 7);
                    b[j] = *(const bf16x8*)&Bb[r * 64 + sl * 8];
                }
#pragma unroll
                for (int i = 0; i < 4; ++i)
#pragma unroll
                    for (int j = 0; j < 4; ++j)
                        acc[i][j] = mfma16(a[i], b[j], acc[i][j]);
            }
        }
#undef QKV_STAGE

        if (sel == 2) {
            const int bb = tm >> 11;
            const int s0 = tm & 2047;
            const size_t vtb = ((size_t)bb << 10) + tn;
            for (int c32 = 0; c32 < 128; c32 += 32) {
                __syncthreads();
                if ((c32 >> 6) == (wn >> 6)) {
                    const int j0 = (c32 >> 4) & 2;
#pragma unroll
                    for (int jj = 0; jj < 2; ++jj) {
                        const int j  = j0 + jj;
                        const int cc = jj * 16 + l15;
                        const float bj = bias[tn + wn + 16 * j + l15];
#pragma unroll
                        for (int i = 0; i < 4; ++i) {
                            const int rr = wm + 16 * i + quad * 4;
                            *(ushort4*)&Tb[cc][rr] =
                                pk4(acc[i][j][0] + bj, acc[i][j][1] + bj,
                                    acc[i][j][2] + bj, acc[i][j][3] + bj);
                        }
                    }
                }
                __syncthreads();
                {
                    const int c  = tid >> 3;
                    const int ss = (tid & 7) * 16;
                    uint4 v0 = *(const uint4*)&Tb[c][ss];
                    uint4 v1 = *(const uint4*)&Tb[c][ss + 8];
                    u16* dst = &VT[(vtb + c32 + c) * 2048 + s0 + ss];
                    *(uint4*)dst       = v0;
                    *(uint4*)(dst + 8) = v1;
                }
            }
        } else {
#pragma unroll
            for (int j = 0; j < 4; ++j) {
                const int col = tn + wn + 16 * j + l15;
                const float bj = bias[col];
#pragma unroll
                for (int i = 0; i < 4; ++i) {
                    const int row = tm + wm + 16 * i + quad * 4;
#pragma unroll
                    for (int r = 0; r < 4; ++r) {
                        union { float f; unsigned u; } v; v.f = acc[i][j][r] + bj;
                        unsigned rn = v.u + 0x7FFFu + ((v.u >> 16) & 1u);
                        O[(size_t)(row + r) * N + col] = (u16)(rn >> 16);
                    }
                }
            }
        }
    }
}

// ---------------------------------------------------------------------------
// Output projection GEMM (frozen from round 16)
// ---------------------------------------------------------------------------
__global__ __launch_bounds__(256) void gemm_out64(
    const u16* __restrict__ A, const u16* __restrict__ W,
    const float* __restrict__ bias, float* __restrict__ O,
    int M, int N, int K)
{
    __shared__ __attribute__((aligned(16))) u16 As[2][128 * 64];
    __shared__ __attribute__((aligned(16))) u16 Bs[2][64 * 64];

    const int x = blockIdx.x & 7;
    const int L = blockIdx.x >> 3;                 // 0..63
    const int tm = (8 * (x >> 1) + (L & 7)) << 7;  // 32 tiles
    const int tn = (8 * (x & 1) + (L >> 3)) << 6;  // 16 tiles

    const int tid  = threadIdx.x;
    const int lane = tid & 63;
    const int w    = tid >> 6;
    const int l15  = lane & 15;
    const int quad = lane >> 4;

    const int wm = (w >> 1) << 6;
    const int wn = (w & 1) << 5;

    f32x4 acc[4][2];
#pragma unroll
    for (int i = 0; i < 4; ++i)
#pragma unroll
        for (int j = 0; j < 2; ++j) acc[i][j] = f32x4{0.f, 0.f, 0.f, 0.f};

    const int lr  = lane >> 3;
    const int lcc = lane & 7;
    const int scc = lcc ^ lr;
    const u16* Ag = A + (size_t)(tm + 32 * w + lr) * K + scc * 8;
    const u16* Wg = W + (size_t)(tn + 16 * w + lr) * K + scc * 8;
    u16* Al = &As[0][(32 * w + lr) * 64 + lcc * 8];
    u16* Bl = &Bs[0][(16 * w + lr) * 64 + lcc * 8];

#define OUT_STAGE(bi, k0)                                                      \
    do {                                                                       \
        _Pragma("unroll")                                                      \
        for (int m = 0; m < 4; ++m)                                            \
            async16(Ag + (k0) + (size_t)m * 8 * K, Al + (bi) * 8192 + m * 512);\
        _Pragma("unroll")                                                      \
        for (int m = 0; m < 2; ++m)                                            \
            async16(Wg + (k0) + (size_t)m * 8 * K, Bl + (bi) * 4096 + m * 512);\
    } while (0)

    const int nt = K >> 6;                         // 16
    OUT_STAGE(0, 0);
    for (int t = 0; t < nt; ++t) {
        const int cur = t & 1;
        asm volatile("s_waitcnt vmcnt(0)" ::: "memory");
        __syncthreads();
        if (t + 1 < nt) OUT_STAGE(cur ^ 1, (t + 1) * 64);
        const u16* Ab = As[cur];
        const u16* Bb = Bs[cur];
#pragma unroll
        for (int kk = 0; kk < 2; ++kk) {
            bf16x8 a[4], b[2];
#pragma unroll
            for (int i = 0; i < 4; ++i) {
                const int r  = wm + 16 * i + l15;
                const int sl = (kk * 4 + quad) ^ (r & 7);
                a[i] = *(const bf16x8*)&Ab[r * 64 + sl * 8];
            }
#pragma unroll
            for (int j = 0; j < 2; ++j) {
                const int r  = wn + 16 * j + l15;
                const int sl = (kk * 4 + quad) ^ (r & 7);
                b[j] = *(const bf16x8*)&Bb[r * 64 + sl * 8];
            }
#pragma unroll
            for (int i = 0; i < 4; ++i)
#pragma unroll
                for (int j = 0; j < 2; ++j)
                    acc[i][j] = mfma16(a[i], b[j], acc[i][j]);
        }
    }
#undef OUT_STAGE

#pragma unroll
    for (int j = 0; j < 2; ++j) {
        const int col = tn + wn + 16 * j + l15;
        const float bj = bias[col];
#pragma unroll
        for (int i = 0; i < 4; ++i) {
            const int row = tm + wm + 16 * i + quad * 4;
#pragma unroll
            for (int r = 0; r < 4; ++r)
                O[(size_t)(row + r) * N + col] = acc[i][j][r] + bj;
        }
    }
}

// ---------------------------------------------------------------------------
// attn11 (frozen from round 19)
// ---------------------------------------------------------------------------
__device__ __forceinline__ bf16x8 rdt(const u16* base, int t, int l15, int cc) {
    const int r = t * 16 + l15;
    const int c = (cc & 3) ^ ((r >> 1) & 3);
    return *(const bf16x8*)(base + (cc >> 2) * 2048 + r * 32 + c * 8);
}

#define QK_EXP(Z, PROW, QG, MASKED, RSV, KB)                                   \
    do {                                                                       \
        _Pragma("unroll")                                                      \
        for (int t = 0; t < 4; ++t) {                                          \
            float e0 = fexp2(fmaf((Z)[t][0], SC, -16.0f));                     \
            float e1 = fexp2(fmaf((Z)[t][1], SC, -16.0f));                     \
            float e2 = fexp2(fmaf((Z)[t][2], SC, -16.0f));                     \
            float e3 = fexp2(fmaf((Z)[t][3], SC, -16.0f));                     \
            if (MASKED) {                                                      \
                const int kb = (KB) + t * 16 + quad * 4;                       \
                if (kb + 0 > (QG)) e0 = 0.f;                                   \
                if (kb + 1 > (QG)) e1 = 0.f;                                   \
                if (kb + 2 > (QG)) e2 = 0.f;                                   \
                if (kb + 3 > (QG)) e3 = 0.f;                                   \
            }                                                                  \
            (RSV)[0] += e0; (RSV)[1] += e1;                                    \
            (RSV)[2] += e2; (RSV)[3] += e3;                                    \
            *(ushort4*)((PROW) + (((2 * t + whi) ^ sl7) << 3) + woff) =        \
                pk4(e0, e1, e2, e3);                                           \
        }                                                                      \
    } while (0)

__global__ __launch_bounds__(256, 4) void attn11(
    const u16* __restrict__ Q, const u16* __restrict__ Kb,
    const u16* __restrict__ VT, u16* __restrict__ ctx)
{
    __shared__ __attribute__((aligned(16))) u16 Kt[2][4096];
    __shared__ __attribute__((aligned(16))) u16 Vt[2][4096];
    __shared__ __attribute__((aligned(16))) u16 Pt[4][16][64];

    const int tid  = threadIdx.x;
    const int lane = tid & 63;
    const int wid  = tid >> 6;
    const int l15  = lane & 15;
    const int quad = lane >> 4;
    const int sl7  = l15 & 7;
    const int whi  = quad >> 1;
    const int woff = (quad & 1) * 4;

    const int hb = blockIdx.x & 31;
    const int h  = hb & 15, b = hb >> 4;
    const int ti = blockIdx.x >> 5;          // 0..31
    const int tq = ti >> 3, to = ti & 7;
    const int g4 = (tq == 0) ? to
                 : (tq == 1) ? (15 - to)
                 : (tq == 2) ? (16 + to)
                 :             (31 - to);    // quartet index 0..31
    const int s  = 4 * g4 + wid;             // Q group 0..127
    const int NT = g4 + 1;                   // KV 64-tiles (same for all waves)

    const size_t rowbase = (size_t)b * 2048;
    const int cbase = h * 64;
    const u16* kbase = Kb + rowbase * 1024 + cbase;
    const u16* vbase = VT + ((size_t)b * 1024 + cbase) * 2048;

    const int qg = s * 16 + l15;
    const u16* qp = Q + (rowbase + qg) * 1024 + cbase + quad * 8;
    const bf16x8 q0 = *(const bf16x8*)qp, q1 = *(const bf16x8*)(qp + 32);

    const int sr  = tid >> 2;
    const int sc0 = (((tid & 3) ^ ((sr >> 1) & 3)) << 3);
    const u16* kg = kbase + (size_t)sr * 1024 + sc0;
    const u16* vg = vbase + (size_t)sr * 2048 + sc0;

    f32x4 o[4];
#pragma unroll
    for (int i = 0; i < 4; ++i) o[i] = f32x4{0, 0, 0, 0};
    f32x4 rsv = {0, 0, 0, 0};
    const float SC = 0.18033688011112042f;

    u16 (*ptw)[64] = Pt[wid];
    u16* const pr = &ptw[l15][0];
    const int pof0 = (quad ^ sl7) << 3;
    const int pof1 = ((quad | 4) ^ sl7) << 3;

#define STAGE(buf, Tt)                                                         \
    do {                                                                       \
        const u16* kq = kg + (size_t)(Tt) * 65536;                             \
        const u16* vq = vg + (Tt) * 64;                                        \
        async16(kq,      &Kt[buf][tid * 8]);                                   \
        async16(kq + 32, &Kt[buf][2048 + tid * 8]);                            \
        async16(vq,      &Vt[buf][tid * 8]);                                   \
        async16(vq + 32, &Vt[buf][2048 + tid * 8]);                            \
    } while (0)

    STAGE(0, 0);

    for (int T = 0; T < NT; ++T) {
        const int cur = T & 1;
        asm volatile("s_waitcnt vmcnt(0)" ::: "memory");
        __syncthreads();
        if (T + 1 < NT) STAGE(cur ^ 1, T + 1);

        const u16* KT = Kt[cur];
        const u16* VL = Vt[cur];

        // ---- QK^T ----
        f32x4 z[4];
        __builtin_amdgcn_s_setprio(1);
#pragma unroll
        for (int t = 0; t < 4; ++t) {
            const bf16x8 kA = rdt(KT, t, l15, quad);
            const bf16x8 kB = rdt(KT, t, l15, quad + 4);
            f32x4 zz = {0, 0, 0, 0};
            zz = mfma16(kA, q0, zz);
            zz = mfma16(kB, q1, zz);
            z[t] = zz;
        }
        __builtin_amdgcn_s_setprio(0);

        // ---- exp + pack (mask only on the diagonal tile) ----
        if (T == NT - 1) QK_EXP(z, pr, qg, 1, rsv, T * 64);
        else             QK_EXP(z, pr, qg, 0, rsv, T * 64);

        // ---- P fragments ----
        const bf16x8 pb0 = *(const bf16x8*)(pr + pof0);
        const bf16x8 pb1 = *(const bf16x8*)(pr + pof1);

        // ---- PV ----
        __builtin_amdgcn_s_setprio(1);
#pragma unroll
        for (int t = 0; t < 4; ++t) {
            const bf16x8 vA = rdt(VL, t, l15, quad);
            const bf16x8 vB = rdt(VL, t, l15, quad + 4);
            o[t] = mfma16(vA, pb0, o[t]);
            o[t] = mfma16(vB, pb1, o[t]);
        }
        __builtin_amdgcn_s_setprio(0);
    }
#undef STAGE

    float rs = (rsv[0] + rsv[1]) + (rsv[2] + rsv[3]);
    rs += __shfl_xor(rs, 16); rs += __shfl_xor(rs, 32);
    const float inv = 1.0f / rs;
#pragma unroll
    for (int t = 0; t < 4; ++t) {
        *(ushort4*)&ctx[(rowbase + qg) * 1024 + cbase + t * 16 + quad * 4] =
            pk4(o[t][0] * inv, o[t][1] * inv, o[t][2] * inv, o[t][3] * inv);
    }
}

extern "C" void kernel_launch(void* const* d_in, const int* in_sizes, int n_in,
                              void* d_out, int out_size, void* d_ws, size_t ws_size,
                              hipStream_t stream) {
    const float* x  = (const float*)d_in[0];
    const float* Wq = (const float*)d_in[1];
    const float* bq = (const float*)d_in[2];
    const float* Wk = (const float*)d_in[3];
    const float* bk = (const float*)d_in[4];
    const float* Wv = (const float*)d_in[5];
    const float* bv = (const float*)d_in[6];
    const float* Wo = (const float*)d_in[7];
    const float* bo = (const float*)d_in[8];
    float* out = (float*)d_out;

    const int N = 1024, K = 1024;
    const int M = in_sizes[0] / K;           // 4096
    const size_t MN = (size_t)M * N;
    const size_t WN = (size_t)N * K;

    u16* xb  = (u16*)d_ws;
    u16* wqb = xb  + MN;
    u16* wkb = wqb + WN;
    u16* wvb = wkb + WN;
    u16* wob = wvb + WN;
    u16* q   = wob + WN;
    u16* kb  = q   + MN;
    u16* vt  = kb  + MN;                     // V^T: [b*1024 + h*64 + d][s]
    u16* ctx = q;                            // alias: disjoint per-wave strips

    cast_all<<<dim3(1024, 5), 256, 0, stream>>>(
        x, Wq, Wk, Wv, Wo, xb, wqb, wkb, wvb, wob);

    // persistent 2-tile grid: 512 blocks cover the 768 logical tiles
    gemm_qkv<<<dim3(512), 256, 0, stream>>>(
        xb, wqb, wkb, wvb, bq, bk, bv, q, kb, vt, M, N, K);

    attn11<<<dim3(1024), 256, 0, stream>>>(q, kb, vt, ctx);

    gemm_out64<<<dim3(512), 256, 0, stream>>>(
        ctx, wob, bo, out, M, N, K);
}

// Round 9
// 177.739 us; speedup vs baseline: 1.0488x; 1.0109x over previous
//
#include <hip/hip_runtime.h>
#include <stdint.h>

typedef unsigned short u16;
typedef __bf16 bf16x8 __attribute__((ext_vector_type(8)));
typedef __bf16 bf16x4v __attribute__((ext_vector_type(4)));
typedef float f32x4 __attribute__((ext_vector_type(4)));

typedef __attribute__((address_space(3))) uint32_t lds_u32;
typedef __attribute__((address_space(1))) uint32_t glb_u32;

__device__ __forceinline__ f32x4 mfma16(bf16x8 a, bf16x8 b, f32x4 c) {
    return __builtin_amdgcn_mfma_f32_16x16x32_bf16(a, b, c, 0, 0, 0);
}

// 4x f32 -> bf16 via native cvt (RNE), reinterpreted as ushort4
__device__ __forceinline__ ushort4 pk4(float a, float b, float c, float d) {
    bf16x4v v;
    v[0] = (__bf16)a; v[1] = (__bf16)b; v[2] = (__bf16)c; v[3] = (__bf16)d;
    union { bf16x4v v; ushort4 u; } cv; cv.v = v; return cv.u;
}

// raw v_exp_f32 (skip ocml wrapper)
__device__ __forceinline__ float fexp2(float x) {
    return __builtin_amdgcn_exp2f(x);
}

// async global->LDS, 16B per lane (LDS dest = wave base + lane*16)
__device__ __forceinline__ void async16(const u16* g, u16* l) {
    __builtin_amdgcn_global_load_lds((glb_u32*)(uintptr_t)(const void*)g,
                                     (lds_u32*)l, 16, 0, 0);
}

// ---------------------------------------------------------------------------
// fp32 -> bf16 casts (unchanged)
// ---------------------------------------------------------------------------
__global__ __launch_bounds__(256) void cast_all(
    const float* __restrict__ x,
    const float* __restrict__ w0, const float* __restrict__ w1,
    const float* __restrict__ w2, const float* __restrict__ w3,
    u16* __restrict__ xo, u16* __restrict__ o0, u16* __restrict__ o1,
    u16* __restrict__ o2, u16* __restrict__ o3)
{
    const int s = blockIdx.y;
    const int i = (blockIdx.x * 256 + threadIdx.x) * 4;
    if (s == 0) {
#pragma unroll
        for (int c = 0; c < 4; ++c) {
            const int j = i + c * (1 << 20);
            float4 v = *(const float4*)(x + j);
            *(ushort4*)(xo + j) = pk4(v.x, v.y, v.z, v.w);
        }
    } else {
        const float* in = s == 1 ? w0 : (s == 2 ? w1 : (s == 3 ? w2 : w3));
        u16* out       = s == 1 ? o0 : (s == 2 ? o1 : (s == 3 ? o2 : o3));
        float4 v = *(const float4*)(in + i);
        *(ushort4*)(out + i) = pk4(v.x, v.y, v.z, v.w);
    }
}

// ---------------------------------------------------------------------------
// QKV GEMM (restored round-16 version: BK=64 dbuf + prefetch, 768 blocks --
// measured best; round-21's persistent 2-tile variant was ~1.5us worse)
// ---------------------------------------------------------------------------
__global__ __launch_bounds__(256) void gemm_qkv(
    const u16* __restrict__ A,
    const u16* __restrict__ W0, const u16* __restrict__ W1, const u16* __restrict__ W2,
    const float* __restrict__ B0, const float* __restrict__ B1, const float* __restrict__ B2,
    u16* __restrict__ O0, u16* __restrict__ O1,
    u16* __restrict__ VT,
    int M, int N, int K)
{
    const int x = blockIdx.x & 7;
    const int L = blockIdx.x >> 3;                 // 0..95
    const int tm = (8 * (x >> 1) + (L & 7)) << 7;  // 32 tm tiles
    const int tnsel = 12 * (x & 1) + (L >> 3);     // 0..23
    const int sel = tnsel >> 3;
    const int tn  = (tnsel & 7) << 7;

    const u16* W      = sel == 0 ? W0 : (sel == 1 ? W1 : W2);
    const float* bias = sel == 0 ? B0 : (sel == 1 ? B1 : B2);
    u16* O            = sel == 0 ? O0 : O1;        // sel==2 -> VT path

    __shared__ __attribute__((aligned(16))) u16 As[2][128 * 64];
    __shared__ __attribute__((aligned(16))) u16 Bs[2][128 * 64];
    u16 (*Tb)[136] = (u16 (*)[136])As;             // union: post-K-loop only

    const int tid  = threadIdx.x;
    const int lane = tid & 63;
    const int w    = tid >> 6;
    const int l15  = lane & 15;
    const int quad = lane >> 4;

    const int wm = (w >> 1) << 6;
    const int wn = (w & 1) << 6;

    f32x4 acc[4][4];
#pragma unroll
    for (int i = 0; i < 4; ++i)
#pragma unroll
        for (int j = 0; j < 4; ++j) acc[i][j] = f32x4{0.f, 0.f, 0.f, 0.f};

    const int lr  = lane >> 3;                     // 0..7
    const int lcc = lane & 7;                      // dest chunk
    const int scc = lcc ^ lr;                      // source chunk (row&7 == lr)
    const u16* Ag = A + (size_t)(tm + 32 * w + lr) * K + scc * 8;
    const u16* Wg = W + (size_t)(tn + 32 * w + lr) * K + scc * 8;
    u16* Al = &As[0][(32 * w + lr) * 64 + lcc * 8];
    u16* Bl = &Bs[0][(32 * w + lr) * 64 + lcc * 8];

#define QKV_STAGE(bi, k0)                                                      \
    do {                                                                       \
        _Pragma("unroll")                                                      \
        for (int m = 0; m < 4; ++m) {                                          \
            async16(Ag + (k0) + (size_t)m * 8 * K, Al + (bi) * 8192 + m * 512);\
            async16(Wg + (k0) + (size_t)m * 8 * K, Bl + (bi) * 8192 + m * 512);\
        }                                                                      \
    } while (0)

    const int nt = K >> 6;                         // 16
    QKV_STAGE(0, 0);
    for (int t = 0; t < nt; ++t) {
        const int cur = t & 1;
        asm volatile("s_waitcnt vmcnt(0)" ::: "memory");
        __syncthreads();
        if (t + 1 < nt) QKV_STAGE(cur ^ 1, (t + 1) * 64);
        const u16* Ab = As[cur];
        const u16* Bb = Bs[cur];
#pragma unroll
        for (int kk = 0; kk < 2; ++kk) {
            bf16x8 a[4], b[4];
#pragma unroll
            for (int i = 0; i < 4; ++i) {
                const int r  = wm + 16 * i + l15;
                const int sl = (kk * 4 + quad) ^ (r & 7);
                a[i] = *(const bf16x8*)&Ab[r * 64 + sl * 8];
            }
#pragma unroll
            for (int j = 0; j < 4; ++j) {
                const int r  = wn + 16 * j + l15;
                const int sl = (kk * 4 + quad) ^ (r & 7);
                b[j] = *(const bf16x8*)&Bb[r * 64 + sl * 8];
            }
#pragma unroll
            for (int i = 0; i < 4; ++i)
#pragma unroll
                for (int j = 0; j < 4; ++j)
                    acc[i][j] = mfma16(a[i], b[j], acc[i][j]);
        }
    }
#undef QKV_STAGE

    if (sel == 2) {
        const int bb = tm >> 11;
        const int s0 = tm & 2047;
        const size_t vtb = ((size_t)bb << 10) + tn;
        for (int c32 = 0; c32 < 128; c32 += 32) {
            __syncthreads();
            if ((c32 >> 6) == (wn >> 6)) {
                const int j0 = (c32 >> 4) & 2;
#pragma unroll
                for (int jj = 0; jj < 2; ++jj) {
                    const int j  = j0 + jj;
                    const int cc = jj * 16 + l15;
                    const float bj = bias[tn + wn + 16 * j + l15];
#pragma unroll
                    for (int i = 0; i < 4; ++i) {
                        const int rr = wm + 16 * i + quad * 4;
                        *(ushort4*)&Tb[cc][rr] =
                            pk4(acc[i][j][0] + bj, acc[i][j][1] + bj,
                                acc[i][j][2] + bj, acc[i][j][3] + bj);
                    }
                }
            }
            __syncthreads();
            {
                const int c  = tid >> 3;
                const int ss = (tid & 7) * 16;
                uint4 v0 = *(const uint4*)&Tb[c][ss];
                uint4 v1 = *(const uint4*)&Tb[c][ss + 8];
                u16* dst = &VT[(vtb + c32 + c) * 2048 + s0 + ss];
                *(uint4*)dst       = v0;
                *(uint4*)(dst + 8) = v1;
            }
        }
    } else {
#pragma unroll
        for (int j = 0; j < 4; ++j) {
            const int col = tn + wn + 16 * j + l15;
            const float bj = bias[col];
#pragma unroll
            for (int i = 0; i < 4; ++i) {
                const int row = tm + wm + 16 * i + quad * 4;
#pragma unroll
                for (int r = 0; r < 4; ++r) {
                    union { float f; unsigned u; } v; v.f = acc[i][j][r] + bj;
                    unsigned rn = v.u + 0x7FFFu + ((v.u >> 16) & 1u);
                    O[(size_t)(row + r) * N + col] = (u16)(rn >> 16);
                }
            }
        }
    }
}

// ---------------------------------------------------------------------------
// Output projection GEMM (frozen from round 16)
// ---------------------------------------------------------------------------
__global__ __launch_bounds__(256) void gemm_out64(
    const u16* __restrict__ A, const u16* __restrict__ W,
    const float* __restrict__ bias, float* __restrict__ O,
    int M, int N, int K)
{
    __shared__ __attribute__((aligned(16))) u16 As[2][128 * 64];
    __shared__ __attribute__((aligned(16))) u16 Bs[2][64 * 64];

    const int x = blockIdx.x & 7;
    const int L = blockIdx.x >> 3;                 // 0..63
    const int tm = (8 * (x >> 1) + (L & 7)) << 7;  // 32 tiles
    const int tn = (8 * (x & 1) + (L >> 3)) << 6;  // 16 tiles

    const int tid  = threadIdx.x;
    const int lane = tid & 63;
    const int w    = tid >> 6;
    const int l15  = lane & 15;
    const int quad = lane >> 4;

    const int wm = (w >> 1) << 6;
    const int wn = (w & 1) << 5;

    f32x4 acc[4][2];
#pragma unroll
    for (int i = 0; i < 4; ++i)
#pragma unroll
        for (int j = 0; j < 2; ++j) acc[i][j] = f32x4{0.f, 0.f, 0.f, 0.f};

    const int lr  = lane >> 3;
    const int lcc = lane & 7;
    const int scc = lcc ^ lr;
    const u16* Ag = A + (size_t)(tm + 32 * w + lr) * K + scc * 8;
    const u16* Wg = W + (size_t)(tn + 16 * w + lr) * K + scc * 8;
    u16* Al = &As[0][(32 * w + lr) * 64 + lcc * 8];
    u16* Bl = &Bs[0][(16 * w + lr) * 64 + lcc * 8];

#define OUT_STAGE(bi, k0)                                                      \
    do {                                                                       \
        _Pragma("unroll")                                                      \
        for (int m = 0; m < 4; ++m)                                            \
            async16(Ag + (k0) + (size_t)m * 8 * K, Al + (bi) * 8192 + m * 512);\
        _Pragma("unroll")                                                      \
        for (int m = 0; m < 2; ++m)                                            \
            async16(Wg + (k0) + (size_t)m * 8 * K, Bl + (bi) * 4096 + m * 512);\
    } while (0)

    const int nt = K >> 6;                         // 16
    OUT_STAGE(0, 0);
    for (int t = 0; t < nt; ++t) {
        const int cur = t & 1;
        asm volatile("s_waitcnt vmcnt(0)" ::: "memory");
        __syncthreads();
        if (t + 1 < nt) OUT_STAGE(cur ^ 1, (t + 1) * 64);
        const u16* Ab = As[cur];
        const u16* Bb = Bs[cur];
#pragma unroll
        for (int kk = 0; kk < 2; ++kk) {
            bf16x8 a[4], b[2];
#pragma unroll
            for (int i = 0; i < 4; ++i) {
                const int r  = wm + 16 * i + l15;
                const int sl = (kk * 4 + quad) ^ (r & 7);
                a[i] = *(const bf16x8*)&Ab[r * 64 + sl * 8];
            }
#pragma unroll
            for (int j = 0; j < 2; ++j) {
                const int r  = wn + 16 * j + l15;
                const int sl = (kk * 4 + quad) ^ (r & 7);
                b[j] = *(const bf16x8*)&Bb[r * 64 + sl * 8];
            }
#pragma unroll
            for (int i = 0; i < 4; ++i)
#pragma unroll
                for (int j = 0; j < 2; ++j)
                    acc[i][j] = mfma16(a[i], b[j], acc[i][j]);
        }
    }
#undef OUT_STAGE

#pragma unroll
    for (int j = 0; j < 2; ++j) {
        const int col = tn + wn + 16 * j + l15;
        const float bj = bias[col];
#pragma unroll
        for (int i = 0; i < 4; ++i) {
            const int row = tm + wm + 16 * i + quad * 4;
#pragma unroll
            for (int r = 0; r < 4; ++r)
                O[(size_t)(row + r) * N + col] = acc[i][j][r] + bj;
        }
    }
}

// ---------------------------------------------------------------------------
// attn12: round-22. P kept fully in registers via K-row staging permutation.
//  * Insight: QK output lane(l15,quad) holds S for K-row = LDS-row
//    t*16+quad*4+r; PV's B-operand needs P[k=quad*8+e] / P[32+quad*8+e].
//    Stage K-row pi(l) at LDS row l with the bit permutation
//    k = 32*l[5] + 8*l[3:2] + 4*l[4] + l[1:0]; then each lane's 16 exp
//    values are EXACTLY its PV B-operand ks: pb0 = pk4(e[0])||pk4(e[1]),
//    pb1 = pk4(e[2])||pk4(e[3]). Zero shuffles, zero LDS for P.
//  * Deletes per wave-tile: 8 ushort4 LDS writes + 2 b128 reads (~25% of
//    the LDS-pipe budget; attn11 model ~79% LDS-busy) and the exp->LDS->PV
//    wait chain. Pt deleted: LDS 40 -> 32 KB.
//  * Causal mask uses the permuted k: T*64 + ((t&2)<<4) + 8*quad + 4*(t&1) + r.
//  * Staging: source row psr = pi(sr); chunk swizzle unchanged (keyed to
//    dest row). V path and row-sum are permutation-invariant.
// ---------------------------------------------------------------------------
__device__ __forceinline__ bf16x8 rdt(const u16* base, int t, int l15, int cc) {
    const int r = t * 16 + l15;
    const int c = (cc & 3) ^ ((r >> 1) & 3);
    return *(const bf16x8*)(base + (cc >> 2) * 2048 + r * 32 + c * 8);
}

__global__ __launch_bounds__(256, 4) void attn12(
    const u16* __restrict__ Q, const u16* __restrict__ Kb,
    const u16* __restrict__ VT, u16* __restrict__ ctx)
{
    __shared__ __attribute__((aligned(16))) u16 Kt[2][4096];
    __shared__ __attribute__((aligned(16))) u16 Vt[2][4096];

    const int tid  = threadIdx.x;
    const int lane = tid & 63;
    const int wid  = tid >> 6;
    const int l15  = lane & 15;
    const int quad = lane >> 4;

    const int hb = blockIdx.x & 31;
    const int h  = hb & 15, b = hb >> 4;
    const int ti = blockIdx.x >> 5;          // 0..31
    const int tq = ti >> 3, to = ti & 7;
    const int g4 = (tq == 0) ? to
                 : (tq == 1) ? (15 - to)
                 : (tq == 2) ? (16 + to)
                 :             (31 - to);    // quartet index 0..31
    const int s  = 4 * g4 + wid;             // Q group 0..127
    const int NT = g4 + 1;                   // KV 64-tiles (same for all waves)

    const size_t rowbase = (size_t)b * 2048;
    const int cbase = h * 64;
    const u16* kbase = Kb + rowbase * 1024 + cbase;
    const u16* vbase = VT + ((size_t)b * 1024 + cbase) * 2048;

    const int qg = s * 16 + l15;
    const u16* qp = Q + (rowbase + qg) * 1024 + cbase + quad * 8;
    const bf16x8 q0 = *(const bf16x8*)qp, q1 = *(const bf16x8*)(qp + 32);

    // staging: dest row sr = tid>>2, dest chunk tid&3; K source row is the
    // bit-permuted psr (P-in-register layout); chunk perm keyed to dest row.
    const int sr  = tid >> 2;
    const int psr = (sr & 0x23) | ((sr & 0x0C) << 1) | ((sr & 0x10) >> 2);
    const int sc0 = (((tid & 3) ^ ((sr >> 1) & 3)) << 3);
    const u16* kg = kbase + (size_t)psr * 1024 + sc0;
    const u16* vg = vbase + (size_t)sr * 2048 + sc0;

    f32x4 o[4];
#pragma unroll
    for (int i = 0; i < 4; ++i) o[i] = f32x4{0, 0, 0, 0};
    f32x4 rsv = {0, 0, 0, 0};
    const float SC = 0.18033688011112042f;

#define STAGE(buf, Tt)                                                         \
    do {                                                                       \
        const u16* kq = kg + (size_t)(Tt) * 65536;                             \
        const u16* vq = vg + (Tt) * 64;                                        \
        async16(kq,      &Kt[buf][tid * 8]);                                   \
        async16(kq + 32, &Kt[buf][2048 + tid * 8]);                            \
        async16(vq,      &Vt[buf][tid * 8]);                                   \
        async16(vq + 32, &Vt[buf][2048 + tid * 8]);                            \
    } while (0)

    STAGE(0, 0);

    for (int T = 0; T < NT; ++T) {
        const int cur = T & 1;
        asm volatile("s_waitcnt vmcnt(0)" ::: "memory");
        __syncthreads();
        if (T + 1 < NT) STAGE(cur ^ 1, T + 1);

        const u16* KT = Kt[cur];
        const u16* VL = Vt[cur];

        // ---- QK^T ----
        f32x4 z[4];
        __builtin_amdgcn_s_setprio(1);
#pragma unroll
        for (int t = 0; t < 4; ++t) {
            const bf16x8 kA = rdt(KT, t, l15, quad);
            const bf16x8 kB = rdt(KT, t, l15, quad + 4);
            f32x4 zz = {0, 0, 0, 0};
            zz = mfma16(kA, q0, zz);
            zz = mfma16(kB, q1, zz);
            z[t] = zz;
        }
        __builtin_amdgcn_s_setprio(0);

        // ---- exp (mask only on diagonal tile; permuted k formula) ----
        float e[4][4];
        if (T == NT - 1) {
#pragma unroll
            for (int t = 0; t < 4; ++t)
#pragma unroll
                for (int r = 0; r < 4; ++r) {
                    const int kreal = T * 64 + ((t & 2) << 4) + (quad << 3)
                                    + ((t & 1) << 2) + r;
                    float v = fmaf(z[t][r], SC, -16.0f);
                    const float ev = fexp2(v);
                    e[t][r] = (kreal > qg) ? 0.f : ev;
                    rsv[r] += e[t][r];
                }
        } else {
#pragma unroll
            for (int t = 0; t < 4; ++t)
#pragma unroll
                for (int r = 0; r < 4; ++r) {
                    e[t][r] = fexp2(fmaf(z[t][r], SC, -16.0f));
                    rsv[r] += e[t][r];
                }
        }

        // ---- pack P fragments in-register (no LDS) ----
        union { ushort4 q[2]; bf16x8 v; } cv0, cv1;
        cv0.q[0] = pk4(e[0][0], e[0][1], e[0][2], e[0][3]);
        cv0.q[1] = pk4(e[1][0], e[1][1], e[1][2], e[1][3]);
        cv1.q[0] = pk4(e[2][0], e[2][1], e[2][2], e[2][3]);
        cv1.q[1] = pk4(e[3][0], e[3][1], e[3][2], e[3][3]);
        const bf16x8 pb0 = cv0.v;
        const bf16x8 pb1 = cv1.v;

        // ---- PV ----
        __builtin_amdgcn_s_setprio(1);
#pragma unroll
        for (int t = 0; t < 4; ++t) {
            const bf16x8 vA = rdt(VL, t, l15, quad);
            const bf16x8 vB = rdt(VL, t, l15, quad + 4);
            o[t] = mfma16(vA, pb0, o[t]);
            o[t] = mfma16(vB, pb1, o[t]);
        }
        __builtin_amdgcn_s_setprio(0);
    }
#undef STAGE

    float rs = (rsv[0] + rsv[1]) + (rsv[2] + rsv[3]);
    rs += __shfl_xor(rs, 16); rs += __shfl_xor(rs, 32);
    const float inv = 1.0f / rs;
#pragma unroll
    for (int t = 0; t < 4; ++t) {
        *(ushort4*)&ctx[(rowbase + qg) * 1024 + cbase + t * 16 + quad * 4] =
            pk4(o[t][0] * inv, o[t][1] * inv, o[t][2] * inv, o[t][3] * inv);
    }
}

extern "C" void kernel_launch(void* const* d_in, const int* in_sizes, int n_in,
                              void* d_out, int out_size, void* d_ws, size_t ws_size,
                              hipStream_t stream) {
    const float* x  = (const float*)d_in[0];
    const float* Wq = (const float*)d_in[1];
    const float* bq = (const float*)d_in[2];
    const float* Wk = (const float*)d_in[3];
    const float* bk = (const float*)d_in[4];
    const float* Wv = (const float*)d_in[5];
    const float* bv = (const float*)d_in[6];
    const float* Wo = (const float*)d_in[7];
    const float* bo = (const float*)d_in[8];
    float* out = (float*)d_out;

    const int N = 1024, K = 1024;
    const int M = in_sizes[0] / K;           // 4096
    const size_t MN = (size_t)M * N;
    const size_t WN = (size_t)N * K;

    u16* xb  = (u16*)d_ws;
    u16* wqb = xb  + MN;
    u16* wkb = wqb + WN;
    u16* wvb = wkb + WN;
    u16* wob = wvb + WN;
    u16* q   = wob + WN;
    u16* kb  = q   + MN;
    u16* vt  = kb  + MN;                     // V^T: [b*1024 + h*64 + d][s]
    u16* ctx = q;                            // alias: disjoint per-wave strips

    cast_all<<<dim3(1024, 5), 256, 0, stream>>>(
        x, Wq, Wk, Wv, Wo, xb, wqb, wkb, wvb, wob);

    gemm_qkv<<<dim3(768), 256, 0, stream>>>(
        xb, wqb, wkb, wvb, bq, bk, bv, q, kb, vt, M, N, K);

    attn12<<<dim3(1024), 256, 0, stream>>>(q, kb, vt, ctx);

    gemm_out64<<<dim3(512), 256, 0, stream>>>(
        ctx, wob, bo, out, M, N, K);
}